// Round 2
// baseline (10325.507 us; speedup 1.0000x reference)
//
#include <hip/hip_runtime.h>
#include <math.h>

// Persistent greedy transformer decoder, MI355X (gfx950).
// B=8, D=512, NH=8 (hd=64), H=2048, NL=2, V=32000, L=48.
// Round-3: single 64-block sync domain. No helper blocks.
//   - 64 blocks, (batch,head)=(widx>>3,widx&7). Layer stack with 64-wide
//     relaxed barriers (8/step). QKV+attention fused, KV cache in LDS.
//   - Logits GEMV done by the same 64 blocks with CACHED loads: out_w
//     (65.5 MB) is L3-resident, so steps >=1 never touch HBM for it.
//     One barrier after logits; every block reduces the 64x8 candidate
//     table locally -> next token. The whole 256-block handshake of the
//     previous version (x3 publish, flag poll, 256-done spin) is gone.
// dlog stores stay nontemporal (pure output stream, don't pollute caches).

#define NBK 64
#define NTH 512
#define NGRP 32

namespace cfg {
constexpr int D  = 512;
constexpr int HF = 2048;
constexpr int V  = 32000;
constexpr int TMAX = 64;        // LDS KV slots (>= L)
constexpr float EPS = 1e-5f;
constexpr float PE_NEG = -0.017988946039015984f;  // -ln(10000)/512

// workspace float offsets; [0..1023] = barrier counters
constexpr size_t O_CAV  = 1024;
constexpr size_t O_CAC  = O_CAV + 2 * 8 * 512;
constexpr size_t O_ATT  = O_CAC + 2 * 8 * 512;
constexpr size_t O_Y1   = O_ATT + 8 * 512;
constexpr size_t O_Y2   = O_Y1  + 8 * 512;
constexpr size_t O_HFF  = O_Y2  + 8 * 512;
constexpr size_t O_CAND = O_HFF + 8 * 2048;
}

typedef float f4v __attribute__((ext_vector_type(4)));

// device-coherent (cross-XCD) accesses for inter-block communication
__device__ __forceinline__ float ld_dev(const float* p) {
  return __hip_atomic_load(p, __ATOMIC_RELAXED, __HIP_MEMORY_SCOPE_AGENT);
}
__device__ __forceinline__ void st_dev(float* p, float v) {
  __hip_atomic_store(p, v, __ATOMIC_RELAXED, __HIP_MEMORY_SCOPE_AGENT);
}
union F2U { float2 f; unsigned long long u; };
__device__ __forceinline__ float2 ld_dev2(const float2* p) {
  F2U x; x.u = __hip_atomic_load((const unsigned long long*)p, __ATOMIC_RELAXED, __HIP_MEMORY_SCOPE_AGENT);
  return x.f;
}
__device__ __forceinline__ void st_dev2(float2* p, float2 v) {
  F2U x; x.f = v;
  __hip_atomic_store((unsigned long long*)p, x.u, __ATOMIC_RELAXED, __HIP_MEMORY_SCOPE_AGENT);
}

// GEMV stage: out[b][r] = dot(xs_row[b], W[r]) + bias[r], K = 512, 8 batches.
// Rows strided r = grp*NW + bid (NW = #participating blocks).
template <typename EPI>
__device__ __forceinline__ void gemv512(const float* __restrict__ W,
                                        const float* __restrict__ bias,
                                        int R, int NW, int bid,
                                        const float* xs, EPI&& epi) {
  const int tid = threadIdx.x;
  const int gl  = tid & 15;
  const int grp = tid >> 4;
  for (int r = grp * NW + bid; r < R; r += NW * NGRP) {
    const f4v* wr = (const f4v*)(W + (size_t)r * cfg::D);
    float acc[8] = {0.f, 0.f, 0.f, 0.f, 0.f, 0.f, 0.f, 0.f};
#pragma unroll
    for (int i = 0; i < 8; ++i) {
      const f4v w = wr[gl + 16 * i];
#pragma unroll
      for (int b = 0; b < 8; ++b) {
        const float4 a = ((const float4*)(xs + b * cfg::D))[gl + 16 * i];
        acc[b] = fmaf(w[0], a.x, acc[b]);
        acc[b] = fmaf(w[1], a.y, acc[b]);
        acc[b] = fmaf(w[2], a.z, acc[b]);
        acc[b] = fmaf(w[3], a.w, acc[b]);
      }
    }
#pragma unroll
    for (int b = 0; b < 8; ++b) {
      float v = acc[b];
      v += __shfl_xor(v, 1);
      v += __shfl_xor(v, 2);
      v += __shfl_xor(v, 4);
      v += __shfl_xor(v, 8);
      acc[b] = v;
    }
    if (gl < 8) {
      float v = acc[gl];
      if (bias) v += bias[r];
      epi(gl, r, v);
    }
  }
}

__launch_bounds__(NTH)
__global__ void decoder_persistent(
    const float* __restrict__ memory, const float* __restrict__ embedding,
    const float* __restrict__ sa_in_w, const float* __restrict__ sa_in_b,
    const float* __restrict__ sa_out_w, const float* __restrict__ sa_out_b,
    const float* __restrict__ ca_in_w, const float* __restrict__ ca_in_b,
    const float* __restrict__ ca_out_w, const float* __restrict__ ca_out_b,
    const float* __restrict__ ff1_w, const float* __restrict__ ff1_b,
    const float* __restrict__ ff2_w, const float* __restrict__ ff2_b,
    const float* __restrict__ ln1_g, const float* __restrict__ ln1_b,
    const float* __restrict__ ln2_g, const float* __restrict__ ln2_b,
    const float* __restrict__ ln3_g, const float* __restrict__ ln3_b,
    const float* __restrict__ out_w, const float* __restrict__ out_b,
    const int* __restrict__ max_len_p,
    float* __restrict__ dout, float* __restrict__ wsf) {
  using namespace cfg;
  __shared__ __align__(16) float xs[8192];            // 32 KB activations
  __shared__ float kch[2][TMAX][64];                  // 32 KB LDS K cache
  __shared__ float vch[2][TMAX][64];                  // 32 KB LDS V cache
  __shared__ float q_s[64];
  __shared__ float p_l[64];
  __shared__ float div_ls[256];                       // PE frequency table
  __shared__ float2 redc[64];
  __shared__ float2 gcand[NGRP * 8];
  __shared__ int tok_ls[8];

  const int tid  = threadIdx.x;
  const int w    = tid >> 6;    // wave id == batch row for LN mapping
  const int lane = tid & 63;
  const int col0 = lane * 8;
  const int gl   = tid & 15;
  const int grp  = tid >> 4;
  const int L    = max_len_p[0];
  const int widx = (int)blockIdx.x;
  const int ab = widx >> 3;     // worker batch
  const int ah = widx & 7;      // worker head (== XCD under %8 round-robin)

  unsigned* wbcnt    = (unsigned*)wsf;        // 8 subs, stride 32
  unsigned* wbmaster = (unsigned*)wsf + 256;
  unsigned* wbgen    = (unsigned*)wsf + 288;

  float*  cav  = wsf + O_CAV;
  float*  cac  = wsf + O_CAC;
  float*  attb = wsf + O_ATT;
  float*  y1   = wsf + O_Y1;
  float*  y2   = wsf + O_Y2;
  float*  hff  = wsf + O_HFF;
  float2* cand = (float2*)(wsf + O_CAND);
  float*  dlog = dout + (size_t)8 * L;

  unsigned wbarn = 0;

  // 64-block barrier (8 subs x 8 arrivals). Relaxed; __syncthreads drains
  // vmcnt so prior sc1 write-through stores are globally visible first.
  auto wsync = [&]() {
    __syncthreads();
    if (tid == 0) {
      ++wbarn;
      unsigned old = __hip_atomic_fetch_add(&wbcnt[(widx & 7) * 32], 1u,
                                            __ATOMIC_RELAXED, __HIP_MEMORY_SCOPE_AGENT);
      if ((old & 7u) == 7u) {
        unsigned o2 = __hip_atomic_fetch_add(wbmaster, 1u,
                                             __ATOMIC_RELAXED, __HIP_MEMORY_SCOPE_AGENT);
        if ((o2 & 7u) == 7u)
          __hip_atomic_store(wbgen, wbarn, __ATOMIC_RELAXED, __HIP_MEMORY_SCOPE_AGENT);
      }
      while (__hip_atomic_load(wbgen, __ATOMIC_RELAXED, __HIP_MEMORY_SCOPE_AGENT) < wbarn)
        __builtin_amdgcn_s_sleep(1);
    }
    __syncthreads();
  };

  // wave-local LayerNorm of row w held in v[8] (cols col0..col0+7)
  auto wave_ln = [&](float (&v)[8], const float* g, const float* bta) {
    float s = 0.f, s2 = 0.f;
#pragma unroll
    for (int j = 0; j < 8; ++j) { s += v[j]; s2 = fmaf(v[j], v[j], s2); }
#pragma unroll
    for (int m = 1; m < 64; m <<= 1) { s += __shfl_xor(s, m); s2 += __shfl_xor(s2, m); }
    const float mean = s * (1.f / 512.f);
    const float var  = s2 * (1.f / 512.f) - mean * mean;
    const float inv  = 1.0f / sqrtf(var + EPS);
    const float4 g0 = ((const float4*)(g + col0))[0], g1 = ((const float4*)(g + col0))[1];
    const float4 b0 = ((const float4*)(bta + col0))[0], b1 = ((const float4*)(bta + col0))[1];
    const float gg[8] = {g0.x, g0.y, g0.z, g0.w, g1.x, g1.y, g1.z, g1.w};
    const float bb[8] = {b0.x, b0.y, b0.z, b0.w, b1.x, b1.y, b1.z, b1.w};
#pragma unroll
    for (int j = 0; j < 8; ++j) v[j] = (v[j] - mean) * inv * gg[j] + bb[j];
  };

  // ================= init =================
  if (tid < 256) div_ls[tid] = expf((float)(2 * tid) * PE_NEG);
  {
    const int gtid = widx * NTH + tid;
    if (gtid < 2 * 8 * 512) {  // v_mem = mem @ Wv.T + bv
      const int b = gtid & 7, r = (gtid >> 3) & 511, l = gtid >> 12;
      const float4* a4 = (const float4*)(memory + (size_t)b * 512);
      const float4* w4 = (const float4*)(ca_in_w + ((size_t)l * 1536 + 1024 + r) * 512);
      float s = 0.f;
      for (int i = 0; i < 128; ++i) {
        const float4 a = a4[i], ww = w4[i];
        s = fmaf(a.x, ww.x, s); s = fmaf(a.y, ww.y, s);
        s = fmaf(a.z, ww.z, s); s = fmaf(a.w, ww.w, s);
      }
      st_dev(&cav[((size_t)l * 8 + b) * 512 + r], s + ca_in_b[l * 1536 + 1024 + r]);
    }
  }
  wsync();
  {
    const int gtid = widx * NTH + tid;
    if (gtid < 2 * 8 * 512) {  // ca_const = v_mem @ Wout.T + bout
      const int b = gtid & 7, r = (gtid >> 3) & 511, l = gtid >> 12;
      const float* a = cav + ((size_t)l * 8 + b) * 512;
      const float4* w4 = (const float4*)(ca_out_w + ((size_t)l * 512 + r) * 512);
      float s = 0.f;
      for (int i = 0; i < 128; ++i) {
        const float4 ww = w4[i];
        s = fmaf(ld_dev(a + 4 * i + 0), ww.x, s);
        s = fmaf(ld_dev(a + 4 * i + 1), ww.y, s);
        s = fmaf(ld_dev(a + 4 * i + 2), ww.z, s);
        s = fmaf(ld_dev(a + 4 * i + 3), ww.w, s);
      }
      st_dev(&cac[((size_t)l * 8 + b) * 512 + r], s + ca_out_b[l * 512 + r]);
    }
  }
  wsync();

  // ================= autoregressive decode =================
  float x0r[8];   // residual for LN1
  float x2r[8];   // LN2 output (residual for LN3)
  if (tid < 8) tok_ls[tid] = 1;  // SOS
  __syncthreads();

  for (int t = 0; t < L; ++t) {
    for (int l = 0; l < 2; ++l) {
      // ---------- build layer input rows into xs (+ x0r regs) ----------
      if (l == 0) {
        const int tok = tok_ls[w];
        const float4* e4 = (const float4*)(embedding + (size_t)tok * 512 + col0);
        const float4 e0 = e4[0], e1 = e4[1];
        float v[8] = {e0.x, e0.y, e0.z, e0.w, e1.x, e1.y, e1.z, e1.w};
#pragma unroll
        for (int j = 0; j < 8; ++j) {
          const int c = col0 + j;
          const float ang = (float)t * div_ls[c >> 1];
          v[j] += (c & 1) ? cosf(ang) : sinf(ang);
          x0r[j] = v[j];
          xs[w * 512 + c] = v[j];
        }
        __syncthreads();
      } else {
        float v[8];
#pragma unroll
        for (int j = 0; j < 8; ++j) v[j] = x2r[j] + ld_dev(y2 + (size_t)w * 512 + col0 + j);
        wave_ln(v, ln3_g, ln3_b);  // layer-0 LN3
#pragma unroll
        for (int j = 0; j < 8; ++j) { x0r[j] = v[j]; xs[w * 512 + col0 + j] = v[j]; }
        __syncthreads();
      }

      // ---------- fused QKV-slice + attention (block-local, no barrier) ----
      {
        // 192 rows: 64 q + 64 k + 64 v dims for (ab, ah), batch ab only.
        // Blocks sharing ah share these weight rows and the same XCD L2.
        for (int it = 0; it < 6; ++it) {
          const int rr = grp + 32 * it;            // 0..191
          const int type = rr >> 6, d = rr & 63;
          const int wrow = type * 512 + ah * 64 + d;
          const float4* wr = (const float4*)(sa_in_w + ((size_t)l * 1536 + wrow) * 512);
          const float4* a4 = (const float4*)(xs + (size_t)ab * 512);
          float s = 0.f;
#pragma unroll
          for (int i = 0; i < 8; ++i) {
            const float4 ww = wr[gl + 16 * i], a = a4[gl + 16 * i];
            s = fmaf(ww.x, a.x, s); s = fmaf(ww.y, a.y, s);
            s = fmaf(ww.z, a.z, s); s = fmaf(ww.w, a.w, s);
          }
          s += __shfl_xor(s, 1);
          s += __shfl_xor(s, 2);
          s += __shfl_xor(s, 4);
          s += __shfl_xor(s, 8);
          if (gl == 0) {
            s += sa_in_b[l * 1536 + wrow];
            if (type == 0)      q_s[d] = s;
            else if (type == 1) kch[l][t][d] = s;
            else                vch[l][t][d] = s;
          }
        }
        __syncthreads();
        // scores: wave w handles keys w, w+8, ...
        for (int j = w; j <= t; j += 8) {
          float s = q_s[lane] * kch[l][j][lane];
          s += __shfl_xor(s, 1);
          s += __shfl_xor(s, 2);
          s += __shfl_xor(s, 4);
          s += __shfl_xor(s, 8);
          s += __shfl_xor(s, 16);
          s += __shfl_xor(s, 32);
          if (lane == 0) p_l[j] = s * 0.125f;
        }
        __syncthreads();
        float mx = -3.4e38f;
        for (int j = 0; j <= t; ++j) mx = fmaxf(mx, p_l[j]);
        __syncthreads();
        if (tid <= t) p_l[tid] = expf(p_l[tid] - mx);
        __syncthreads();
        if (w == 0) {   // PV + normalize, 64 lanes = 64 dims
          float den = 0.f, o = 0.f;
          for (int j = 0; j <= t; ++j) {
            const float p = p_l[j];
            den += p;
            o = fmaf(p, vch[l][j][lane], o);
          }
          st_dev(&attb[(size_t)ab * 512 + ah * 64 + lane], o / den);
        }
      }
      wsync();  // barrier A: attn slices visible

      // ---------- attention out-proj ----------
      for (int j = tid; j < 2048; j += NTH)
        ((float2*)xs)[j] = ld_dev2((const float2*)attb + j);
      __syncthreads();
      gemv512(sa_out_w + (size_t)l * 512 * 512, sa_out_b + l * 512, 512,
              NBK, widx, xs,
              [&](int b, int r, float val) { st_dev(&y1[(size_t)b * 512 + r], val); });
      wsync();  // barrier B: y1 complete

      // ---------- LN1 + ca_const + LN2 (in regs) then FF1 ----------
      {
        float v[8];
#pragma unroll
        for (int j = 0; j < 8; ++j) v[j] = x0r[j] + ld_dev(y1 + (size_t)w * 512 + col0 + j);
        wave_ln(v, ln1_g + l * 512, ln1_b + l * 512);
#pragma unroll
        for (int j = 0; j < 8; ++j) v[j] += ld_dev(cac + ((size_t)l * 8 + w) * 512 + col0 + j);
        wave_ln(v, ln2_g + l * 512, ln2_b + l * 512);
#pragma unroll
        for (int j = 0; j < 8; ++j) { x2r[j] = v[j]; xs[w * 512 + col0 + j] = v[j]; }
        __syncthreads();
      }
      gemv512(ff1_w + (size_t)l * HF * 512, ff1_b + l * HF, HF,
              NBK, widx, xs,
              [&](int b, int r, float val) {
                st_dev(&hff[(size_t)b * HF + r], fmaxf(val, 0.f));
              });
      wsync();  // barrier C: hff complete

      // ---------- FF2 (K=2048, two 1024-wide tiles) ----------
      {
        const bool act = (grp < 8);                 // 512 rows, 1 row/group
        const int r = (grp & 7) * 64 + widx;
        float acc[8] = {0.f, 0.f, 0.f, 0.f, 0.f, 0.f, 0.f, 0.f};
        for (int tile = 0; tile < 2; ++tile) {
          __syncthreads();
          for (int j = tid; j < 4096; j += NTH)
            ((float2*)xs)[j] = ld_dev2((const float2*)hff + (size_t)(j >> 9) * 1024 +
                                       tile * 512 + (j & 511));
          __syncthreads();
          if (act) {
            const float4* wr = (const float4*)(ff2_w + ((size_t)l * 512 + r) * HF +
                                               (size_t)tile * 1024);
#pragma unroll
            for (int i = 0; i < 16; ++i) {
              const float4 ww = wr[gl + 16 * i];
#pragma unroll
              for (int b2 = 0; b2 < 8; ++b2) {
                const float4 a = ((const float4*)xs)[b2 * 256 + gl + 16 * i];
                acc[b2] = fmaf(ww.x, a.x, acc[b2]);
                acc[b2] = fmaf(ww.y, a.y, acc[b2]);
                acc[b2] = fmaf(ww.z, a.z, acc[b2]);
                acc[b2] = fmaf(ww.w, a.w, acc[b2]);
              }
            }
          }
        }
        if (act) {
#pragma unroll
          for (int b2 = 0; b2 < 8; ++b2) {
            float v = acc[b2];
            v += __shfl_xor(v, 1);
            v += __shfl_xor(v, 2);
            v += __shfl_xor(v, 4);
            v += __shfl_xor(v, 8);
            acc[b2] = v;
          }
          if (gl < 8) st_dev(&y2[(size_t)gl * 512 + r], acc[gl] + ff2_b[l * 512 + r]);
        }
      }
      wsync();  // barrier D: y2 complete
    }  // layer loop

    // ---------- final LN3 -> x3 in xs (every block, redundant+local) ----------
    {
      float v[8];
#pragma unroll
      for (int j = 0; j < 8; ++j) v[j] = x2r[j] + ld_dev(y2 + (size_t)w * 512 + col0 + j);
      wave_ln(v, ln3_g + 512, ln3_b + 512);
#pragma unroll
      for (int j = 0; j < 8; ++j) xs[w * 512 + col0 + j] = v[j];
      __syncthreads();
    }

    // ---------- logits (cached out_w: L3-resident) + per-block argmax ----------
    {
      float bestv = -3.4e38f, besti = 0.f;
      gemv512(out_w, out_b, V, NBK, widx, xs,
              [&](int b, int r, float val) {
                __builtin_nontemporal_store(val, &dlog[((size_t)b * L + t) * V + r]);
                if (val > bestv) { bestv = val; besti = (float)r; }
              });
      if (gl < 8) gcand[grp * 8 + gl] = make_float2(bestv, besti);
      __syncthreads();
      if (tid < 8) {
        float bv = -3.4e38f, bi = 0.f;
        for (int g2 = 0; g2 < NGRP; ++g2) {
          const float2 cv = gcand[g2 * 8 + tid];
          if (cv.x > bv || (cv.x == bv && cv.y < bi)) { bv = cv.x; bi = cv.y; }
        }
        st_dev2(&cand[(size_t)widx * 8 + tid], make_float2(bv, bi));
      }
    }
    wsync();  // barrier E: all 64 candidate rows visible

    // ---------- every block reduces 64x8 candidates locally ----------
    {
      if (tid < 64) {
        const int b = tid & 7, j0 = (tid >> 3) << 3;
        float bv = -3.4e38f, bi = 0.f;
#pragma unroll
        for (int jj = 0; jj < 8; ++jj) {
          const float2 cv = ld_dev2(&cand[(size_t)(j0 + jj) * 8 + b]);
          if (cv.x > bv || (cv.x == bv && cv.y < bi)) { bv = cv.x; bi = cv.y; }
        }
        redc[tid] = make_float2(bv, bi);
      }
      __syncthreads();
      if (tid < 8) {
        float bv = -3.4e38f, bi = 0.f;
        for (int c = 0; c < 8; ++c) {
          const float2 cv = redc[c * 8 + tid];
          if (cv.x > bv || (cv.x == bv && cv.y < bi)) { bv = cv.x; bi = cv.y; }
        }
        tok_ls[tid] = (int)bi;
        if (widx == 0) dout[(size_t)tid * L + t] = bi;
      }
      __syncthreads();
    }
  }  // t loop
}

extern "C" void kernel_launch(void* const* d_in, const int* in_sizes, int n_in,
                              void* d_out, int out_size, void* d_ws, size_t ws_size,
                              hipStream_t stream) {
  (void)in_sizes; (void)n_in; (void)out_size; (void)ws_size;
  hipMemsetAsync(d_ws, 0, 4096, stream);  // barrier counters

  const float* memory    = (const float*)d_in[0];
  const float* embedding = (const float*)d_in[1];
  const float* sa_in_w   = (const float*)d_in[2];
  const float* sa_in_b   = (const float*)d_in[3];
  const float* sa_out_w  = (const float*)d_in[4];
  const float* sa_out_b  = (const float*)d_in[5];
  const float* ca_in_w   = (const float*)d_in[6];
  const float* ca_in_b   = (const float*)d_in[7];
  const float* ca_out_w  = (const float*)d_in[8];
  const float* ca_out_b  = (const float*)d_in[9];
  const float* ff1_w     = (const float*)d_in[10];
  const float* ff1_b     = (const float*)d_in[11];
  const float* ff2_w     = (const float*)d_in[12];
  const float* ff2_b     = (const float*)d_in[13];
  const float* ln1_g     = (const float*)d_in[14];
  const float* ln1_b     = (const float*)d_in[15];
  const float* ln2_g     = (const float*)d_in[16];
  const float* ln2_b     = (const float*)d_in[17];
  const float* ln3_g     = (const float*)d_in[18];
  const float* ln3_b     = (const float*)d_in[19];
  const float* out_w     = (const float*)d_in[20];
  const float* out_b     = (const float*)d_in[21];
  const int*   max_len   = (const int*)d_in[22];

  hipLaunchKernelGGL(decoder_persistent, dim3(NBK), dim3(NTH), 0, stream,
                     memory, embedding, sa_in_w, sa_in_b, sa_out_w, sa_out_b,
                     ca_in_w, ca_in_b, ca_out_w, ca_out_b, ff1_w, ff1_b,
                     ff2_w, ff2_b, ln1_g, ln1_b, ln2_g, ln2_b, ln3_g, ln3_b,
                     out_w, out_b, max_len, (float*)d_out, (float*)d_ws);
}

// Round 3
// 5541.104 us; speedup vs baseline: 1.8634x; 1.8634x over previous
//
#include <hip/hip_runtime.h>
#include <math.h>

// Persistent greedy transformer decoder, MI355X (gfx950).
// B=8, D=512, NH=8 (hd=64), H=2048, NL=2, V=32000, L=48.
// Round-4: keep 64-block single sync domain; fix the three mechanical costs
// found in round-3 post-mortem:
//  1) logits epilogue wrote scattered 4B NT stores (28x write amplification,
//     store-queue backpressure) -> now: contiguous 500-row slab per block,
//     LDS-staged, coalesced 2KB-run stores per batch.
//  2) barrier was 3 rounds of serialized same-line atomic RMW at L3
//     (~5-7us each) -> now: RMW-free flag barrier. Arrival = one relaxed
//     store to own cacheline; wave 0 of every block polls all 64 flags in
//     parallel (1 load/lane + ballot). ~1.5us.
//  3) logits weight reads now contiguous per block (DRAM-friendly).

#define NBK 64
#define NTH 512
#define NGRP 32

namespace cfg {
constexpr int D  = 512;
constexpr int HF = 2048;
constexpr int V  = 32000;
constexpr int TMAX = 64;        // LDS KV slots (>= L)
constexpr int VPB  = V / NBK;   // 500 logits rows per block
constexpr float EPS = 1e-5f;
constexpr float PE_NEG = -0.017988946039015984f;  // -ln(10000)/512

// workspace float offsets; [0..2047] = barrier flags (64 x 128B)
constexpr size_t O_CAV  = 4096;
constexpr size_t O_CAC  = O_CAV + 2 * 8 * 512;
constexpr size_t O_ATT  = O_CAC + 2 * 8 * 512;
constexpr size_t O_Y1   = O_ATT + 8 * 512;
constexpr size_t O_Y2   = O_Y1  + 8 * 512;
constexpr size_t O_HFF  = O_Y2  + 8 * 512;
constexpr size_t O_CAND = O_HFF + 8 * 2048;
}

typedef float f4v __attribute__((ext_vector_type(4)));

// device-coherent (cross-XCD) accesses for inter-block communication
__device__ __forceinline__ float ld_dev(const float* p) {
  return __hip_atomic_load(p, __ATOMIC_RELAXED, __HIP_MEMORY_SCOPE_AGENT);
}
__device__ __forceinline__ void st_dev(float* p, float v) {
  __hip_atomic_store(p, v, __ATOMIC_RELAXED, __HIP_MEMORY_SCOPE_AGENT);
}
union F2U { float2 f; unsigned long long u; };
__device__ __forceinline__ float2 ld_dev2(const float2* p) {
  F2U x; x.u = __hip_atomic_load((const unsigned long long*)p, __ATOMIC_RELAXED, __HIP_MEMORY_SCOPE_AGENT);
  return x.f;
}
__device__ __forceinline__ void st_dev2(float2* p, float2 v) {
  F2U x; x.f = v;
  __hip_atomic_store((unsigned long long*)p, x.u, __ATOMIC_RELAXED, __HIP_MEMORY_SCOPE_AGENT);
}
__device__ __forceinline__ unsigned ld_devu(const unsigned* p) {
  return __hip_atomic_load(p, __ATOMIC_RELAXED, __HIP_MEMORY_SCOPE_AGENT);
}
__device__ __forceinline__ void st_devu(unsigned* p, unsigned v) {
  __hip_atomic_store(p, v, __ATOMIC_RELAXED, __HIP_MEMORY_SCOPE_AGENT);
}

// GEMV stage: out[b][r] = dot(xs_row[b], W[r]) + bias[r], K = 512, 8 batches.
// Rows strided r = grp*NW + bid (NW = #participating blocks).
template <typename EPI>
__device__ __forceinline__ void gemv512(const float* __restrict__ W,
                                        const float* __restrict__ bias,
                                        int R, int NW, int bid,
                                        const float* xs, EPI&& epi) {
  const int tid = threadIdx.x;
  const int gl  = tid & 15;
  const int grp = tid >> 4;
  for (int r = grp * NW + bid; r < R; r += NW * NGRP) {
    const f4v* wr = (const f4v*)(W + (size_t)r * cfg::D);
    float acc[8] = {0.f, 0.f, 0.f, 0.f, 0.f, 0.f, 0.f, 0.f};
#pragma unroll
    for (int i = 0; i < 8; ++i) {
      const f4v w = wr[gl + 16 * i];
#pragma unroll
      for (int b = 0; b < 8; ++b) {
        const float4 a = ((const float4*)(xs + b * cfg::D))[gl + 16 * i];
        acc[b] = fmaf(w[0], a.x, acc[b]);
        acc[b] = fmaf(w[1], a.y, acc[b]);
        acc[b] = fmaf(w[2], a.z, acc[b]);
        acc[b] = fmaf(w[3], a.w, acc[b]);
      }
    }
#pragma unroll
    for (int b = 0; b < 8; ++b) {
      float v = acc[b];
      v += __shfl_xor(v, 1);
      v += __shfl_xor(v, 2);
      v += __shfl_xor(v, 4);
      v += __shfl_xor(v, 8);
      acc[b] = v;
    }
    if (gl < 8) {
      float v = acc[gl];
      if (bias) v += bias[r];
      epi(gl, r, v);
    }
  }
}

__launch_bounds__(NTH)
__global__ void decoder_persistent(
    const float* __restrict__ memory, const float* __restrict__ embedding,
    const float* __restrict__ sa_in_w, const float* __restrict__ sa_in_b,
    const float* __restrict__ sa_out_w, const float* __restrict__ sa_out_b,
    const float* __restrict__ ca_in_w, const float* __restrict__ ca_in_b,
    const float* __restrict__ ca_out_w, const float* __restrict__ ca_out_b,
    const float* __restrict__ ff1_w, const float* __restrict__ ff1_b,
    const float* __restrict__ ff2_w, const float* __restrict__ ff2_b,
    const float* __restrict__ ln1_g, const float* __restrict__ ln1_b,
    const float* __restrict__ ln2_g, const float* __restrict__ ln2_b,
    const float* __restrict__ ln3_g, const float* __restrict__ ln3_b,
    const float* __restrict__ out_w, const float* __restrict__ out_b,
    const int* __restrict__ max_len_p,
    float* __restrict__ dout, float* __restrict__ wsf) {
  using namespace cfg;
  __shared__ __align__(16) float xs[8192];            // 32 KB activations
  __shared__ float kch[2][TMAX][64];                  // 32 KB LDS K cache
  __shared__ float vch[2][TMAX][64];                  // 32 KB LDS V cache
  __shared__ float ltile[8][VPB + 16];                // 16.5 KB logits tile
  __shared__ float q_s[64];
  __shared__ float p_l[64];
  __shared__ float div_ls[256];                       // PE frequency table
  __shared__ float2 redc[64];
  __shared__ float2 gcand[NGRP * 8];
  __shared__ int tok_ls[8];

  const int tid  = threadIdx.x;
  const int w    = tid >> 6;    // wave id == batch row for LN mapping
  const int lane = tid & 63;
  const int col0 = lane * 8;
  const int gl   = tid & 15;
  const int grp  = tid >> 4;
  const int L    = max_len_p[0];
  const int widx = (int)blockIdx.x;
  const int ab = widx >> 3;     // worker batch
  const int ah = widx & 7;      // worker head (== XCD under %8 round-robin)

  unsigned* wflag = (unsigned*)wsf;   // 64 flags, stride 32 u32 (128 B)

  float*  cav  = wsf + O_CAV;
  float*  cac  = wsf + O_CAC;
  float*  attb = wsf + O_ATT;
  float*  y1   = wsf + O_Y1;
  float*  y2   = wsf + O_Y2;
  float*  hff  = wsf + O_HFF;
  float2* cand = (float2*)(wsf + O_CAND);
  float*  dlog = dout + (size_t)8 * L;

  unsigned wbarn = 0;

  // RMW-free 64-block barrier. Arrival: one relaxed store to own line.
  // Detection: wave 0 polls all 64 flags in parallel.  __syncthreads before
  // arrival drains vmcnt, so this block's write-through data stores are at
  // the coherence point before the flag store (same ordering contract the
  // RMW barrier relied on).
  auto wsync = [&]() {
    __syncthreads();
    ++wbarn;
    if (tid == 0) st_devu(&wflag[widx * 32], wbarn);
    if (w == 0) {
      while (true) {
        const unsigned v = ld_devu(&wflag[lane * 32]);
        if (__ballot(v < wbarn) == 0ull) break;
        __builtin_amdgcn_s_sleep(1);
      }
    }
    __syncthreads();
  };

  // wave-local LayerNorm of row w held in v[8] (cols col0..col0+7)
  auto wave_ln = [&](float (&v)[8], const float* g, const float* bta) {
    float s = 0.f, s2 = 0.f;
#pragma unroll
    for (int j = 0; j < 8; ++j) { s += v[j]; s2 = fmaf(v[j], v[j], s2); }
#pragma unroll
    for (int m = 1; m < 64; m <<= 1) { s += __shfl_xor(s, m); s2 += __shfl_xor(s2, m); }
    const float mean = s * (1.f / 512.f);
    const float var  = s2 * (1.f / 512.f) - mean * mean;
    const float inv  = 1.0f / sqrtf(var + EPS);
    const float4 g0 = ((const float4*)(g + col0))[0], g1 = ((const float4*)(g + col0))[1];
    const float4 b0 = ((const float4*)(bta + col0))[0], b1 = ((const float4*)(bta + col0))[1];
    const float gg[8] = {g0.x, g0.y, g0.z, g0.w, g1.x, g1.y, g1.z, g1.w};
    const float bb[8] = {b0.x, b0.y, b0.z, b0.w, b1.x, b1.y, b1.z, b1.w};
#pragma unroll
    for (int j = 0; j < 8; ++j) v[j] = (v[j] - mean) * inv * gg[j] + bb[j];
  };

  // ================= init =================
  if (tid < 256) div_ls[tid] = expf((float)(2 * tid) * PE_NEG);
  {
    const int gtid = widx * NTH + tid;
    if (gtid < 2 * 8 * 512) {  // v_mem = mem @ Wv.T + bv
      const int b = gtid & 7, r = (gtid >> 3) & 511, l = gtid >> 12;
      const float4* a4 = (const float4*)(memory + (size_t)b * 512);
      const float4* w4 = (const float4*)(ca_in_w + ((size_t)l * 1536 + 1024 + r) * 512);
      float s = 0.f;
      for (int i = 0; i < 128; ++i) {
        const float4 a = a4[i], ww = w4[i];
        s = fmaf(a.x, ww.x, s); s = fmaf(a.y, ww.y, s);
        s = fmaf(a.z, ww.z, s); s = fmaf(a.w, ww.w, s);
      }
      st_dev(&cav[((size_t)l * 8 + b) * 512 + r], s + ca_in_b[l * 1536 + 1024 + r]);
    }
  }
  wsync();
  {
    const int gtid = widx * NTH + tid;
    if (gtid < 2 * 8 * 512) {  // ca_const = v_mem @ Wout.T + bout
      const int b = gtid & 7, r = (gtid >> 3) & 511, l = gtid >> 12;
      const float* a = cav + ((size_t)l * 8 + b) * 512;
      const float4* w4 = (const float4*)(ca_out_w + ((size_t)l * 512 + r) * 512);
      float s = 0.f;
      for (int i = 0; i < 128; ++i) {
        const float4 ww = w4[i];
        s = fmaf(ld_dev(a + 4 * i + 0), ww.x, s);
        s = fmaf(ld_dev(a + 4 * i + 1), ww.y, s);
        s = fmaf(ld_dev(a + 4 * i + 2), ww.z, s);
        s = fmaf(ld_dev(a + 4 * i + 3), ww.w, s);
      }
      st_dev(&cac[((size_t)l * 8 + b) * 512 + r], s + ca_out_b[l * 512 + r]);
    }
  }
  wsync();

  // ================= autoregressive decode =================
  float x0r[8];   // residual for LN1
  float x2r[8];   // LN2 output (residual for LN3)
  if (tid < 8) tok_ls[tid] = 1;  // SOS
  __syncthreads();

  for (int t = 0; t < L; ++t) {
    for (int l = 0; l < 2; ++l) {
      // ---------- build layer input rows into xs (+ x0r regs) ----------
      if (l == 0) {
        const int tok = tok_ls[w];
        const float4* e4 = (const float4*)(embedding + (size_t)tok * 512 + col0);
        const float4 e0 = e4[0], e1 = e4[1];
        float v[8] = {e0.x, e0.y, e0.z, e0.w, e1.x, e1.y, e1.z, e1.w};
#pragma unroll
        for (int j = 0; j < 8; ++j) {
          const int c = col0 + j;
          const float ang = (float)t * div_ls[c >> 1];
          v[j] += (c & 1) ? cosf(ang) : sinf(ang);
          x0r[j] = v[j];
          xs[w * 512 + c] = v[j];
        }
        __syncthreads();
      } else {
        float v[8];
#pragma unroll
        for (int j = 0; j < 8; ++j) v[j] = x2r[j] + ld_dev(y2 + (size_t)w * 512 + col0 + j);
        wave_ln(v, ln3_g, ln3_b);  // layer-0 LN3
#pragma unroll
        for (int j = 0; j < 8; ++j) { x0r[j] = v[j]; xs[w * 512 + col0 + j] = v[j]; }
        __syncthreads();
      }

      // ---------- fused QKV-slice + attention (block-local, no barrier) ----
      {
        // 192 rows: 64 q + 64 k + 64 v dims for (ab, ah), batch ab only.
        for (int it = 0; it < 6; ++it) {
          const int rr = grp + 32 * it;            // 0..191
          const int type = rr >> 6, d = rr & 63;
          const int wrow = type * 512 + ah * 64 + d;
          const float4* wr = (const float4*)(sa_in_w + ((size_t)l * 1536 + wrow) * 512);
          const float4* a4 = (const float4*)(xs + (size_t)ab * 512);
          float s = 0.f;
#pragma unroll
          for (int i = 0; i < 8; ++i) {
            const float4 ww = wr[gl + 16 * i], a = a4[gl + 16 * i];
            s = fmaf(ww.x, a.x, s); s = fmaf(ww.y, a.y, s);
            s = fmaf(ww.z, a.z, s); s = fmaf(ww.w, a.w, s);
          }
          s += __shfl_xor(s, 1);
          s += __shfl_xor(s, 2);
          s += __shfl_xor(s, 4);
          s += __shfl_xor(s, 8);
          if (gl == 0) {
            s += sa_in_b[l * 1536 + wrow];
            if (type == 0)      q_s[d] = s;
            else if (type == 1) kch[l][t][d] = s;
            else                vch[l][t][d] = s;
          }
        }
        __syncthreads();
        // scores: wave w handles keys w, w+8, ...
        for (int j = w; j <= t; j += 8) {
          float s = q_s[lane] * kch[l][j][lane];
          s += __shfl_xor(s, 1);
          s += __shfl_xor(s, 2);
          s += __shfl_xor(s, 4);
          s += __shfl_xor(s, 8);
          s += __shfl_xor(s, 16);
          s += __shfl_xor(s, 32);
          if (lane == 0) p_l[j] = s * 0.125f;
        }
        __syncthreads();
        float mx = -3.4e38f;
        for (int j = 0; j <= t; ++j) mx = fmaxf(mx, p_l[j]);
        __syncthreads();
        if (tid <= t) p_l[tid] = expf(p_l[tid] - mx);
        __syncthreads();
        if (w == 0) {   // PV + normalize, 64 lanes = 64 dims
          float den = 0.f, o = 0.f;
          for (int j = 0; j <= t; ++j) {
            const float p = p_l[j];
            den += p;
            o = fmaf(p, vch[l][j][lane], o);
          }
          st_dev(&attb[(size_t)ab * 512 + ah * 64 + lane], o / den);
        }
      }
      wsync();  // barrier A: attn slices visible

      // ---------- attention out-proj ----------
      for (int j = tid; j < 2048; j += NTH)
        ((float2*)xs)[j] = ld_dev2((const float2*)attb + j);
      __syncthreads();
      gemv512(sa_out_w + (size_t)l * 512 * 512, sa_out_b + l * 512, 512,
              NBK, widx, xs,
              [&](int b, int r, float val) { st_dev(&y1[(size_t)b * 512 + r], val); });
      wsync();  // barrier B: y1 complete

      // ---------- LN1 + ca_const + LN2 (in regs) then FF1 ----------
      {
        float v[8];
#pragma unroll
        for (int j = 0; j < 8; ++j) v[j] = x0r[j] + ld_dev(y1 + (size_t)w * 512 + col0 + j);
        wave_ln(v, ln1_g + l * 512, ln1_b + l * 512);
#pragma unroll
        for (int j = 0; j < 8; ++j) v[j] += ld_dev(cac + ((size_t)l * 8 + w) * 512 + col0 + j);
        wave_ln(v, ln2_g + l * 512, ln2_b + l * 512);
#pragma unroll
        for (int j = 0; j < 8; ++j) { x2r[j] = v[j]; xs[w * 512 + col0 + j] = v[j]; }
        __syncthreads();
      }
      gemv512(ff1_w + (size_t)l * HF * 512, ff1_b + l * HF, HF,
              NBK, widx, xs,
              [&](int b, int r, float val) {
                st_dev(&hff[(size_t)b * HF + r], fmaxf(val, 0.f));
              });
      wsync();  // barrier C: hff complete

      // ---------- FF2 (K=2048, two 1024-wide tiles) ----------
      {
        const bool act = (grp < 8);                 // 512 rows, 1 row/group
        const int r = (grp & 7) * 64 + widx;
        float acc[8] = {0.f, 0.f, 0.f, 0.f, 0.f, 0.f, 0.f, 0.f};
        for (int tile = 0; tile < 2; ++tile) {
          __syncthreads();
          for (int j = tid; j < 4096; j += NTH)
            ((float2*)xs)[j] = ld_dev2((const float2*)hff + (size_t)(j >> 9) * 1024 +
                                       tile * 512 + (j & 511));
          __syncthreads();
          if (act) {
            const float4* wr = (const float4*)(ff2_w + ((size_t)l * 512 + r) * HF +
                                               (size_t)tile * 1024);
#pragma unroll
            for (int i = 0; i < 16; ++i) {
              const float4 ww = wr[gl + 16 * i];
#pragma unroll
              for (int b2 = 0; b2 < 8; ++b2) {
                const float4 a = ((const float4*)xs)[b2 * 256 + gl + 16 * i];
                acc[b2] = fmaf(ww.x, a.x, acc[b2]);
                acc[b2] = fmaf(ww.y, a.y, acc[b2]);
                acc[b2] = fmaf(ww.z, a.z, acc[b2]);
                acc[b2] = fmaf(ww.w, a.w, acc[b2]);
              }
            }
          }
        }
        if (act) {
#pragma unroll
          for (int b2 = 0; b2 < 8; ++b2) {
            float v = acc[b2];
            v += __shfl_xor(v, 1);
            v += __shfl_xor(v, 2);
            v += __shfl_xor(v, 4);
            v += __shfl_xor(v, 8);
            acc[b2] = v;
          }
          if (gl < 8) st_dev(&y2[(size_t)gl * 512 + r], acc[gl] + ff2_b[l * 512 + r]);
        }
      }
      wsync();  // barrier D: y2 complete
    }  // layer loop

    // ---------- final LN3 -> x3 in xs ----------
    {
      float v[8];
#pragma unroll
      for (int j = 0; j < 8; ++j) v[j] = x2r[j] + ld_dev(y2 + (size_t)w * 512 + col0 + j);
      wave_ln(v, ln3_g + 512, ln3_b + 512);
#pragma unroll
      for (int j = 0; j < 8; ++j) xs[w * 512 + col0 + j] = v[j];
      __syncthreads();
    }

    // ---------- logits: contiguous slab [widx*500, widx*500+500) ----------
    {
      const int rbase = widx * VPB;
      float bestv = -3.4e38f, besti = 0.f;   // valid on lanes gl<8
      for (int it = 0; it < 16; ++it) {
        const int rloc = it * 32 + grp;      // 0..511; active < 500
        if (rloc < VPB) {
          const f4v* wr = (const f4v*)(out_w + (size_t)(rbase + rloc) * 512);
          float acc[8] = {0.f, 0.f, 0.f, 0.f, 0.f, 0.f, 0.f, 0.f};
#pragma unroll
          for (int i = 0; i < 8; ++i) {
            const f4v ww = wr[gl + 16 * i];
#pragma unroll
            for (int b = 0; b < 8; ++b) {
              const float4 a = ((const float4*)(xs + b * 512))[gl + 16 * i];
              acc[b] = fmaf(ww[0], a.x, acc[b]);
              acc[b] = fmaf(ww[1], a.y, acc[b]);
              acc[b] = fmaf(ww[2], a.z, acc[b]);
              acc[b] = fmaf(ww[3], a.w, acc[b]);
            }
          }
#pragma unroll
          for (int b = 0; b < 8; ++b) {
            float v = acc[b];
            v += __shfl_xor(v, 1);
            v += __shfl_xor(v, 2);
            v += __shfl_xor(v, 4);
            v += __shfl_xor(v, 8);
            acc[b] = v;
          }
          if (gl < 8) {
            const float val = acc[gl] + out_b[rbase + rloc];
            ltile[gl][rloc] = val;
            if (val > bestv) { bestv = val; besti = (float)(rbase + rloc); }
          }
        }
      }
      if (gl < 8) gcand[grp * 8 + gl] = make_float2(bestv, besti);
      __syncthreads();   // ltile + gcand complete
      // coalesced bulk store: 500 contiguous floats per batch
#pragma unroll
      for (int b = 0; b < 8; ++b) {
        if (tid < VPB)
          __builtin_nontemporal_store(ltile[b][tid],
                                      &dlog[((size_t)b * L + t) * V + rbase + tid]);
      }
      if (tid < 8) {
        float bv = -3.4e38f, bi = 0.f;
        for (int g2 = 0; g2 < NGRP; ++g2) {
          const float2 cv = gcand[g2 * 8 + tid];
          if (cv.x > bv || (cv.x == bv && cv.y < bi)) { bv = cv.x; bi = cv.y; }
        }
        st_dev2(&cand[(size_t)widx * 8 + tid], make_float2(bv, bi));
      }
    }
    wsync();  // barrier E: all 64 candidate rows visible

    // ---------- every block reduces 64x8 candidates locally ----------
    {
      if (tid < 64) {
        const int b = tid & 7, j0 = (tid >> 3) << 3;
        float bv = -3.4e38f, bi = 0.f;
#pragma unroll
        for (int jj = 0; jj < 8; ++jj) {
          const float2 cv = ld_dev2(&cand[(size_t)(j0 + jj) * 8 + b]);
          if (cv.x > bv || (cv.x == bv && cv.y < bi)) { bv = cv.x; bi = cv.y; }
        }
        redc[tid] = make_float2(bv, bi);
      }
      __syncthreads();
      if (tid < 8) {
        float bv = -3.4e38f, bi = 0.f;
        for (int c = 0; c < 8; ++c) {
          const float2 cv = redc[c * 8 + tid];
          if (cv.x > bv || (cv.x == bv && cv.y < bi)) { bv = cv.x; bi = cv.y; }
        }
        tok_ls[tid] = (int)bi;
        if (widx == 0) dout[(size_t)tid * L + t] = bi;
      }
      __syncthreads();
    }
  }  // t loop
}

extern "C" void kernel_launch(void* const* d_in, const int* in_sizes, int n_in,
                              void* d_out, int out_size, void* d_ws, size_t ws_size,
                              hipStream_t stream) {
  (void)in_sizes; (void)n_in; (void)out_size; (void)ws_size;
  hipMemsetAsync(d_ws, 0, 16384, stream);  // barrier flags

  const float* memory    = (const float*)d_in[0];
  const float* embedding = (const float*)d_in[1];
  const float* sa_in_w   = (const float*)d_in[2];
  const float* sa_in_b   = (const float*)d_in[3];
  const float* sa_out_w  = (const float*)d_in[4];
  const float* sa_out_b  = (const float*)d_in[5];
  const float* ca_in_w   = (const float*)d_in[6];
  const float* ca_in_b   = (const float*)d_in[7];
  const float* ca_out_w  = (const float*)d_in[8];
  const float* ca_out_b  = (const float*)d_in[9];
  const float* ff1_w     = (const float*)d_in[10];
  const float* ff1_b     = (const float*)d_in[11];
  const float* ff2_w     = (const float*)d_in[12];
  const float* ff2_b     = (const float*)d_in[13];
  const float* ln1_g     = (const float*)d_in[14];
  const float* ln1_b     = (const float*)d_in[15];
  const float* ln2_g     = (const float*)d_in[16];
  const float* ln2_b     = (const float*)d_in[17];
  const float* ln3_g     = (const float*)d_in[18];
  const float* ln3_b     = (const float*)d_in[19];
  const float* out_w     = (const float*)d_in[20];
  const float* out_b     = (const float*)d_in[21];
  const int*   max_len   = (const int*)d_in[22];

  hipLaunchKernelGGL(decoder_persistent, dim3(NBK), dim3(NTH), 0, stream,
                     memory, embedding, sa_in_w, sa_in_b, sa_out_w, sa_out_b,
                     ca_in_w, ca_in_b, ca_out_w, ca_out_b, ff1_w, ff1_b,
                     ff2_w, ff2_b, ln1_g, ln1_b, ln2_g, ln2_b, ln3_g, ln3_b,
                     out_w, out_b, max_len, (float*)d_out, (float*)d_ws);
}